// Round 7
// baseline (721.260 us; speedup 1.0000x reference)
//
#include <hip/hip_runtime.h>
#include <hip/hip_bf16.h>

typedef __attribute__((ext_vector_type(8))) short  short8;
typedef __attribute__((ext_vector_type(4))) float  f32x4;

#define MFMA16(A,B,C) __builtin_amdgcn_mfma_f32_16x16x32_bf16((A),(B),(C),0,0,0)

// ---- fp32 -> bf16 hi/lo split, pair-packed via cvt_pk (compiler-lowered) ----
// hi = bf16_rne(x); lo = bf16_rne(x - hi). Residual ~2^-17 |x|.
__device__ __forceinline__ void split2(float x0, float x1, unsigned &hp, unsigned &lp) {
    __hip_bfloat162 h = __float22bfloat162_rn(float2{x0, x1});
    union { __hip_bfloat162 b; unsigned u; } uh, ul;
    uh.b = h;
    float f0 = __bfloat162float(h.x);
    float f1 = __bfloat162float(h.y);
    ul.b = __float22bfloat162_rn(float2{x0 - f0, x1 - f1});
    hp = uh.u;
    lp = ul.u;
}

__device__ __forceinline__ void split8(const f32x4 a, const f32x4 b, short8 &h, short8 &l) {
    union { short8 s; unsigned u[4]; } H, L;
    split2(a[0], a[1], H.u[0], L.u[0]);
    split2(a[2], a[3], H.u[1], L.u[1]);
    split2(b[0], b[1], H.u[2], L.u[2]);
    split2(b[2], b[3], H.u[3], L.u[3]);
    h = H.s; l = L.s;
}

// XOR-swizzled byte offset inside a [16 rows][64 bf16] plane (row stride 128B).
__device__ __forceinline__ unsigned swz(unsigned row, unsigned colbyte) {
    return row * 128u + (colbyte ^ ((row & 7u) << 4));
}

// Transposed-MFMA tree level: compute emb^T tiles via mfma(W_frag, h_frag, acc).
// The W B-fragment == W^T A-fragment and h A-fragment == h^T B-fragment, so all
// data fragments keep the R6 layout; only the C side transposes:
//   lane (cidx,g) of wave w holds out[row=cidx][cols 16w+4g .. 16w+4g+3]
// -> packed b64 LDS stores, b64/ dwordx4 global stores.
template<bool LEAF, bool FINAL, int MINW>
__global__ __launch_bounds__(256, MINW)
void grnn_mfma(const float* __restrict__ cont,   // ntiles*16 x 32 (fp32)
               const int*   __restrict__ child,  // ntiles*16 x 2
               const void*  __restrict__ ein_,   // emb_{j+1} hi/lo planes or contents8 fp32
               const float* __restrict__ Wu,     // 32 x 64
               const float* __restrict__ bu,     // 64
               const float* __restrict__ Wh,     // 192 x 64
               const float* __restrict__ bh,     // 64
               void*        __restrict__ eout_,  // hi/lo planes (or fp32 if FINAL)
               int ntiles)
{
    constexpr int NP = LEAF ? 6 : 2;              // planes (single-buffered)
    __shared__ __align__(16) char lds[NP * 2048];

    const int lane = threadIdx.x & 63;
    const int w    = threadIdx.x >> 6;
    const int cidx = lane & 15;   // data-row index (and C-col after transpose)
    const int g    = lane >> 4;   // k-group

    // ---- weight fragments (hi/lo) — same values as R6, now used as A-operand ----
    short8 WhH[6], WhL[6], WuH, WuL;
#pragma unroll
    for (int s = 0; s < 6; ++s) {
        union { short8 s8; unsigned u[4]; } H, L;
#pragma unroll
        for (int q = 0; q < 4; ++q) {
            const int k = 32 * s + 8 * g + 2 * q;
            split2(Wh[k * 64 + 16 * w + cidx], Wh[(k + 1) * 64 + 16 * w + cidx], H.u[q], L.u[q]);
        }
        WhH[s] = H.s8; WhL[s] = L.s8;
    }
    {
        union { short8 s8; unsigned u[4]; } H, L;
#pragma unroll
        for (int q = 0; q < 4; ++q) {
            const int k = 8 * g + 2 * q;
            split2(Wu[k * 64 + 16 * w + cidx], Wu[(k + 1) * 64 + 16 * w + cidx], H.u[q], L.u[q]);
        }
        WuH = H.s8; WuL = L.s8;
    }
    // per-lane 4-col bias vectors (C cols = 16w+4g .. +3)
    const f32x4 bu4 = *(const f32x4*)(bu + 16 * w + 4 * g);
    const f32x4 bh4 = *(const f32x4*)(bh + 16 * w + 4 * g);

    const unsigned short* eb = (const unsigned short*)ein_;
    const float*          ef = (const float*)ein_;
    const unsigned colb = 32u * w + 8u * g;   // byte col of this lane's 4-col group

    for (int t = blockIdx.x; t < ntiles; t += gridDim.x) {
        const int r = t * 16 + cidx;
        const int2 ch = *(const int2*)(child + 2 * r);

        // ---- issue gathers first (consumed after phase 1) ----
        short8 gh[2][2], glo[2][2];   // !LEAF: [side][kstep] hi/lo fragments
        f32x4  xl[2][2];              // LEAF:  [side][half] contents8 fp32
        if (LEAF) {
            const f32x4* pL = (const f32x4*)(ef + (size_t)ch.x * 32 + 8 * g);
            const f32x4* pR = (const f32x4*)(ef + (size_t)ch.y * 32 + 8 * g);
            xl[0][0] = pL[0]; xl[0][1] = pL[1];
            xl[1][0] = pR[0]; xl[1][1] = pR[1];
        } else {
            const unsigned short* pL = eb + (size_t)ch.x * 128 + 8 * g;
            const unsigned short* pR = eb + (size_t)ch.y * 128 + 8 * g;
#pragma unroll
            for (int s = 0; s < 2; ++s) {
                gh [0][s] = *(const short8*)(pL + 32 * s);
                glo[0][s] = *(const short8*)(pL + 64 + 32 * s);
                gh [1][s] = *(const short8*)(pR + 32 * s);
                glo[1][s] = *(const short8*)(pR + 64 + 32 * s);
            }
        }
        const f32x4* pc = (const f32x4*)(cont + (size_t)r * 32 + 8 * g);
        const f32x4 ca = pc[0], cbv = pc[1];

        // ---- phase 1: u^T tiles (K=32), relu, split, b64-stash in LDS ----
        short8 AH, AL;
        split8(ca, cbv, AH, AL);
        f32x4 ua = bu4;
        ua = MFMA16(WuH, AH, ua);
        ua = MFMA16(WuL, AH, ua);
        ua = MFMA16(WuH, AL, ua);

        f32x4 uLa, uRa;
        if (LEAF) {
            split8(xl[0][0], xl[0][1], AH, AL);
            uLa = bu4;
            uLa = MFMA16(WuH, AH, uLa);
            uLa = MFMA16(WuL, AH, uLa);
            uLa = MFMA16(WuH, AL, uLa);
            split8(xl[1][0], xl[1][1], AH, AL);
            uRa = bu4;
            uRa = MFMA16(WuH, AH, uRa);
            uRa = MFMA16(WuL, AH, uRa);
            uRa = MFMA16(WuH, AL, uRa);
        }

        {
            const unsigned off = swz(cidx, colb);
            unsigned h0, l0, h1, l1;
            split2(fmaxf(ua[0], 0.f), fmaxf(ua[1], 0.f), h0, l0);
            split2(fmaxf(ua[2], 0.f), fmaxf(ua[3], 0.f), h1, l1);
            *(uint2*)(lds + (NP - 2) * 2048 + off) = uint2{h0, h1};
            *(uint2*)(lds + (NP - 1) * 2048 + off) = uint2{l0, l1};
            if (LEAF) {
                split2(fmaxf(uLa[0], 0.f), fmaxf(uLa[1], 0.f), h0, l0);
                split2(fmaxf(uLa[2], 0.f), fmaxf(uLa[3], 0.f), h1, l1);
                *(uint2*)(lds + 0 * 2048 + off) = uint2{h0, h1};
                *(uint2*)(lds + 1 * 2048 + off) = uint2{l0, l1};
                split2(fmaxf(uRa[0], 0.f), fmaxf(uRa[1], 0.f), h0, l0);
                split2(fmaxf(uRa[2], 0.f), fmaxf(uRa[3], 0.f), h1, l1);
                *(uint2*)(lds + 2 * 2048 + off) = uint2{h0, h1};
                *(uint2*)(lds + 3 * 2048 + off) = uint2{l0, l1};
            }
        }
        __syncthreads();

        // ---- phase 2: emb^T = relu(Wh^T @ [hL|hR|u]^T + bh) ----
        f32x4 acc0 = bh4;
        f32x4 acc1 = {0.f, 0.f, 0.f, 0.f};
        if (LEAF) {
#pragma unroll
            for (int q = 0; q < 3; ++q) {
#pragma unroll
                for (int s = 0; s < 2; ++s) {
                    const short8 aH = *(const short8*)(lds + (2 * q + 0) * 2048 + swz(cidx, 64 * s + 16 * g));
                    const short8 aL = *(const short8*)(lds + (2 * q + 1) * 2048 + swz(cidx, 64 * s + 16 * g));
                    const int S = 2 * q + s;
                    f32x4 &acc = s ? acc1 : acc0;
                    acc = MFMA16(WhH[S], aH, acc);
                    acc = MFMA16(WhL[S], aH, acc);
                    acc = MFMA16(WhH[S], aL, acc);
                }
            }
        } else {
#pragma unroll
            for (int side = 0; side < 2; ++side) {
#pragma unroll
                for (int s = 0; s < 2; ++s) {
                    const int S = 2 * side + s;
                    f32x4 &acc = side ? acc1 : acc0;
                    acc = MFMA16(WhH[S], gh [side][s], acc);
                    acc = MFMA16(WhL[S], gh [side][s], acc);
                    acc = MFMA16(WhH[S], glo[side][s], acc);
                }
            }
#pragma unroll
            for (int s = 0; s < 2; ++s) {
                const short8 aH = *(const short8*)(lds + 0 * 2048 + swz(cidx, 64 * s + 16 * g));
                const short8 aL = *(const short8*)(lds + 1 * 2048 + swz(cidx, 64 * s + 16 * g));
                const int S = 4 + s;
                f32x4 &acc = s ? acc1 : acc0;
                acc = MFMA16(WhH[S], aH, acc);
                acc = MFMA16(WhL[S], aH, acc);
                acc = MFMA16(WhH[S], aL, acc);
            }
        }

        // ---- store: lane holds out[row=cidx][cols 16w+4g .. +3] ----
        if (FINAL) {
            float* out = (float*)eout_;
            f32x4 v;
#pragma unroll
            for (int i = 0; i < 4; ++i) v[i] = fmaxf(acc0[i] + acc1[i], 0.f);
            *(f32x4*)(out + (size_t)(t * 16 + cidx) * 64 + 16 * w + 4 * g) = v;
        } else {
            char* out = (char*)eout_;
            const size_t rb = (size_t)(t * 16 + cidx) * 256;
            unsigned h0, l0, h1, l1;
            split2(fmaxf(acc0[0] + acc1[0], 0.f), fmaxf(acc0[1] + acc1[1], 0.f), h0, l0);
            split2(fmaxf(acc0[2] + acc1[2], 0.f), fmaxf(acc0[3] + acc1[3], 0.f), h1, l1);
            *(uint2*)(out + rb + colb)       = uint2{h0, h1};
            *(uint2*)(out + rb + 128 + colb) = uint2{l0, l1};
        }
        __syncthreads();
    }
}

extern "C" void kernel_launch(void* const* d_in, const int* in_sizes, int n_in,
                              void* d_out, int out_size, void* d_ws, size_t ws_size,
                              hipStream_t stream) {
    // inputs: contents0..8 = d_in[0..8], children0..7 = d_in[9..16],
    //         Wu = d_in[17], bu = d_in[18], Wh = d_in[19], bh = d_in[20]
    const float* Wu = (const float*)d_in[17];
    const float* bu = (const float*)d_in[18];
    const float* Wh = (const float*)d_in[19];
    const float* bh = (const float*)d_in[20];

    // emb_j stored as bf16 hi/lo planes, 256B/row -> same footprint as fp32
    void* bufA = d_ws;                               // emb7/5/3/1 (max 256 MiB)
    void* bufB = (char*)d_ws + (size_t)268435456;    // emb6/4/2

    const void* ein = d_in[8];  // contents8 (fp32) for the fused leaf level
    for (int j = 7; j >= 0; --j) {
        const int n      = in_sizes[j] / 32;
        const int ntiles = n / 16;
        void* eout = (j == 0) ? d_out : ((j & 1) ? bufA : bufB);
        int blocks = ntiles < 4096 ? ntiles : 4096;
        const float* cont  = (const float*)d_in[j];
        const int*   child = (const int*)d_in[9 + j];
        if (j == 7)
            grnn_mfma<true,  false, 4><<<blocks, 256, 0, stream>>>(cont, child, ein, Wu, bu, Wh, bh, eout, ntiles);
        else if (j == 0)
            grnn_mfma<false, true,  3><<<blocks, 256, 0, stream>>>(cont, child, ein, Wu, bu, Wh, bh, eout, ntiles);
        else
            grnn_mfma<false, false, 3><<<blocks, 256, 0, stream>>>(cont, child, ein, Wu, bu, Wh, bh, eout, ntiles);
        ein = eout;
    }
}

// Round 8
// 570.056 us; speedup vs baseline: 1.2652x; 1.2652x over previous
//
#include <hip/hip_runtime.h>
#include <hip/hip_bf16.h>

typedef __attribute__((ext_vector_type(8))) short  short8;
typedef __attribute__((ext_vector_type(4))) float  f32x4;

#define MFMA16(A,B,C) __builtin_amdgcn_mfma_f32_16x16x32_bf16((A),(B),(C),0,0,0)

// ---- fp32 -> bf16 hi/lo split, pair-packed (cvt_pk path) ----
__device__ __forceinline__ void split2(float x0, float x1, unsigned &hp, unsigned &lp) {
    __hip_bfloat162 h = __float22bfloat162_rn(float2{x0, x1});
    union { __hip_bfloat162 b; unsigned u; } uh, ul;
    uh.b = h;
    float f0 = __bfloat162float(h.x);
    float f1 = __bfloat162float(h.y);
    ul.b = __float22bfloat162_rn(float2{x0 - f0, x1 - f1});
    hp = uh.u; lp = ul.u;
}

__device__ __forceinline__ void split8(const f32x4 a, const f32x4 b, short8 &h, short8 &l) {
    union { short8 s; unsigned u[4]; } H, L;
    split2(a[0], a[1], H.u[0], L.u[0]);
    split2(a[2], a[3], H.u[1], L.u[1]);
    split2(b[0], b[1], H.u[2], L.u[2]);
    split2(b[2], b[3], H.u[3], L.u[3]);
    h = H.s; l = L.s;
}

// XOR-swizzled byte offset inside a [16 rows][64 bf16] plane (row stride 128B).
__device__ __forceinline__ unsigned swz(unsigned row, unsigned colbyte) {
    return row * 128u + (colbyte ^ ((row & 7u) << 4));
}

// async global->LDS, 16B/lane. Global address is PER-LANE; LDS dest must be the
// wave-uniform region base (HW writes base + lane*16).
__device__ __forceinline__ void gld16(const void* g, void* l) {
    __builtin_amdgcn_global_load_lds(
        (const __attribute__((address_space(1))) unsigned int*)g,
        (__attribute__((address_space(3))) unsigned int*)l, 16, 0, 0);
}

// Tree level, transposed-MFMA orientation (R7 math), with block-shared gather
// staging: child-row fragments are wave-invariant, so they are gathered ONCE
// per block via global_load_lds into LDS (B-frag order), double-buffered and
// issued one (mid) / two (leaf) iterations ahead.
template<bool LEAF, bool FINAL>
__global__ __launch_bounds__(256, 4)
void grnn_mfma(const float* __restrict__ cont,   // ntiles*16 x 32 (fp32)
               const int*   __restrict__ child,  // ntiles*16 x 2
               const void*  __restrict__ ein_,   // emb_{j+1} hi/lo planes or contents8 fp32
               const float* __restrict__ Wu,     // 32 x 64
               const float* __restrict__ bu,     // 64
               const float* __restrict__ Wh,     // 192 x 64
               const float* __restrict__ bh,     // 64
               void*        __restrict__ eout_,  // hi/lo planes (fp32 if FINAL)
               int ntiles)
{
    constexpr int STG = LEAF ? 4096 : 8192;   // staged gather bytes per parity
    constexpr int NPL = LEAF ? 6 : 2;         // u planes per parity
    __shared__ __align__(16) char lds[2 * STG + 2 * NPL * 2048];
    char* upl0 = lds + 2 * STG;

    const int lane = threadIdx.x & 63;
    const int w    = threadIdx.x >> 6;
    const int cidx = lane & 15;
    const int g    = lane >> 4;

    // ---- weight fragments (hi/lo), transposed orientation (verified in R7) ----
    short8 WhH[6], WhL[6], WuH, WuL;
#pragma unroll
    for (int s = 0; s < 6; ++s) {
        union { short8 s8; unsigned u[4]; } H, L;
#pragma unroll
        for (int q = 0; q < 4; ++q) {
            const int k = 32 * s + 8 * g + 2 * q;
            split2(Wh[k * 64 + 16 * w + cidx], Wh[(k + 1) * 64 + 16 * w + cidx], H.u[q], L.u[q]);
        }
        WhH[s] = H.s8; WhL[s] = L.s8;
    }
    {
        union { short8 s8; unsigned u[4]; } H, L;
#pragma unroll
        for (int q = 0; q < 4; ++q) {
            const int k = 8 * g + 2 * q;
            split2(Wu[k * 64 + 16 * w + cidx], Wu[(k + 1) * 64 + 16 * w + cidx], H.u[q], L.u[q]);
        }
        WuH = H.s8; WuL = L.s8;
    }
    const f32x4 bu4 = *(const f32x4*)(bu + 16 * w + 4 * g);
    const f32x4 bh4 = *(const f32x4*)(bh + 16 * w + 4 * g);

    const char* eb = (const char*)ein_;
    const unsigned colb = 32u * w + 8u * g;
    const int S = gridDim.x;

    // this wave's staging share
    const int side = w >> 1;   // 0: left child, 1: right child
    const int sub  = w & 1;    // leaf: 16B-half of the 32B row-frag | mid: kstep

    // ---- prologue: stage tile k=0 (and k=1 for leaf), load cont(0) ----
    int t = blockIdx.x;
    {
        const int2 cA = *(const int2*)(child + 2 * (t * 16 + cidx));
        if (LEAF) {
            int t1 = (t + S < ntiles) ? t + S : t;
            const int2 cB = *(const int2*)(child + 2 * (t1 * 16 + cidx));
            gld16(eb + (size_t)(side ? cA.y : cA.x) * 128 + sub * 64 + g * 16,
                  lds + 0 * STG + (side * 2 + sub) * 1024);
            gld16(eb + (size_t)(side ? cB.y : cB.x) * 128 + sub * 64 + g * 16,
                  lds + 1 * STG + (side * 2 + sub) * 1024);
        } else {
            const char* sb = eb + (size_t)(side ? cA.y : cA.x) * 256 + sub * 64 + g * 16;
            gld16(sb,       lds + 0 * STG + (side * 4 + sub * 2 + 0) * 1024);
            gld16(sb + 128, lds + 0 * STG + (side * 4 + sub * 2 + 1) * 1024);
        }
    }
    f32x4 cc0, cc1;
    {
        const f32x4* pc = (const f32x4*)(cont + (size_t)(t * 16 + cidx) * 32 + 8 * g);
        cc0 = pc[0]; cc1 = pc[1];
    }
    __syncthreads();   // prologue staging visible

    for (int k = 0; t < ntiles; t += S, ++k) {
        const int pb = k & 1;

        // prefetch: child idx for the tile we will STAGE this iteration, next cont
        int ts = LEAF ? (t + 2 * S) : (t + S);
        if (ts >= ntiles) ts = t;                         // clamped (dead dup)
        const int2 chN = *(const int2*)(child + 2 * (ts * 16 + cidx));
        int tn = (t + S < ntiles) ? t + S : t;
        f32x4 cn0, cn1;
        {
            const f32x4* pc = (const f32x4*)(cont + (size_t)(tn * 16 + cidx) * 32 + 8 * g);
            cn0 = pc[0]; cn1 = pc[1];
        }

        // ---- phase 1: u tiles (K=32), relu, split, stash in u planes[pb] ----
        char* ub = upl0 + pb * (NPL * 2048);
        short8 AH, AL;
        split8(cc0, cc1, AH, AL);
        f32x4 ua = bu4;
        ua = MFMA16(WuH, AH, ua);
        ua = MFMA16(WuL, AH, ua);
        ua = MFMA16(WuH, AL, ua);
        {
            const unsigned off = swz(cidx, colb);
            unsigned h0, l0, h1, l1;
            split2(fmaxf(ua[0], 0.f), fmaxf(ua[1], 0.f), h0, l0);
            split2(fmaxf(ua[2], 0.f), fmaxf(ua[3], 0.f), h1, l1);
            *(uint2*)(ub + (NPL - 2) * 2048 + off) = uint2{h0, h1};
            *(uint2*)(ub + (NPL - 1) * 2048 + off) = uint2{l0, l1};
        }
        if (LEAF) {
            // uL, uR from staged fp32 x-rows (staged 2 iters ago into buf pb)
            const char* xb = lds + pb * STG;
            const unsigned o0 = 512u * (g & 1) + 16u * cidx;   // slot of floats 8g..8g+3
            const unsigned rg = (unsigned)(g >> 1) * 1024u;    // half-region for this g
            const unsigned off = swz(cidx, colb);
#pragma unroll
            for (int sd = 0; sd < 2; ++sd) {
                const char* base = xb + sd * 2048 + rg;
                const f32x4 a = *(const f32x4*)(base + o0);
                const f32x4 b = *(const f32x4*)(base + o0 + 256);
                split8(a, b, AH, AL);
                f32x4 ux = bu4;
                ux = MFMA16(WuH, AH, ux);
                ux = MFMA16(WuL, AH, ux);
                ux = MFMA16(WuH, AL, ux);
                unsigned h0, l0, h1, l1;
                split2(fmaxf(ux[0], 0.f), fmaxf(ux[1], 0.f), h0, l0);
                split2(fmaxf(ux[2], 0.f), fmaxf(ux[3], 0.f), h1, l1);
                *(uint2*)(ub + (2 * sd + 0) * 2048 + off) = uint2{h0, h1};
                *(uint2*)(ub + (2 * sd + 1) * 2048 + off) = uint2{l0, l1};
            }
        }
        __syncthreads();   // u planes + this tile's staged gathers all visible

        // ---- phase 2 ----
        // issue next staging first (max in-flight window: drained at NEXT barrier)
        if (LEAF) {
            gld16(eb + (size_t)(side ? chN.y : chN.x) * 128 + sub * 64 + g * 16,
                  lds + pb * STG + (side * 2 + sub) * 1024);        // tile k+2 -> buf pb
        } else {
            const char* sN = eb + (size_t)(side ? chN.y : chN.x) * 256 + sub * 64 + g * 16;
            gld16(sN,       lds + (pb ^ 1) * STG + (side * 4 + sub * 2 + 0) * 1024);  // k+1
            gld16(sN + 128, lds + (pb ^ 1) * STG + (side * 4 + sub * 2 + 1) * 1024);
        }

        f32x4 acc0 = bh4;
        f32x4 acc1 = {0.f, 0.f, 0.f, 0.f};
        if (LEAF) {
#pragma unroll
            for (int q = 0; q < 3; ++q) {
#pragma unroll
                for (int s = 0; s < 2; ++s) {
                    const short8 aH = *(const short8*)(ub + (2 * q + 0) * 2048 + swz(cidx, 64 * s + 16 * g));
                    const short8 aL = *(const short8*)(ub + (2 * q + 1) * 2048 + swz(cidx, 64 * s + 16 * g));
                    const int Sl = 2 * q + s;
                    f32x4 &acc = s ? acc1 : acc0;
                    acc = MFMA16(WhH[Sl], aH, acc);
                    acc = MFMA16(WhL[Sl], aH, acc);
                    acc = MFMA16(WhH[Sl], aL, acc);
                }
            }
        } else {
            const char* hb = lds + pb * STG;
#pragma unroll
            for (int sd = 0; sd < 2; ++sd) {
#pragma unroll
                for (int s = 0; s < 2; ++s) {
                    const short8 aH = *(const short8*)(hb + (sd * 4 + s * 2 + 0) * 1024 + 16 * lane);
                    const short8 aL = *(const short8*)(hb + (sd * 4 + s * 2 + 1) * 1024 + 16 * lane);
                    const int Sl = 2 * sd + s;
                    f32x4 &acc = sd ? acc1 : acc0;
                    acc = MFMA16(WhH[Sl], aH, acc);
                    acc = MFMA16(WhL[Sl], aH, acc);
                    acc = MFMA16(WhH[Sl], aL, acc);
                }
            }
#pragma unroll
            for (int s = 0; s < 2; ++s) {
                const short8 aH = *(const short8*)(ub + 0 * 2048 + swz(cidx, 64 * s + 16 * g));
                const short8 aL = *(const short8*)(ub + 1 * 2048 + swz(cidx, 64 * s + 16 * g));
                const int Sl = 4 + s;
                f32x4 &acc = s ? acc1 : acc0;
                acc = MFMA16(WhH[Sl], aH, acc);
                acc = MFMA16(WhL[Sl], aH, acc);
                acc = MFMA16(WhH[Sl], aL, acc);
            }
        }

        // ---- store: lane holds out[row=cidx][cols 16w+4g .. +3] (R7 layout) ----
        if (FINAL) {
            float* out = (float*)eout_;
            f32x4 v;
#pragma unroll
            for (int i = 0; i < 4; ++i) v[i] = fmaxf(acc0[i] + acc1[i], 0.f);
            *(f32x4*)(out + (size_t)(t * 16 + cidx) * 64 + 16 * w + 4 * g) = v;
        } else {
            char* out = (char*)eout_;
            const size_t rb = (size_t)(t * 16 + cidx) * 256;
            unsigned h0, l0, h1, l1;
            split2(fmaxf(acc0[0] + acc1[0], 0.f), fmaxf(acc0[1] + acc1[1], 0.f), h0, l0);
            split2(fmaxf(acc0[2] + acc1[2], 0.f), fmaxf(acc0[3] + acc1[3], 0.f), h1, l1);
            *(uint2*)(out + rb + colb)       = uint2{h0, h1};
            *(uint2*)(out + rb + 128 + colb) = uint2{l0, l1};
        }

        cc0 = cn0; cc1 = cn1;
    }
}

extern "C" void kernel_launch(void* const* d_in, const int* in_sizes, int n_in,
                              void* d_out, int out_size, void* d_ws, size_t ws_size,
                              hipStream_t stream) {
    // inputs: contents0..8 = d_in[0..8], children0..7 = d_in[9..16],
    //         Wu = d_in[17], bu = d_in[18], Wh = d_in[19], bh = d_in[20]
    const float* Wu = (const float*)d_in[17];
    const float* bu = (const float*)d_in[18];
    const float* Wh = (const float*)d_in[19];
    const float* bh = (const float*)d_in[20];

    // emb_j stored as bf16 hi/lo planes, 256B/row
    void* bufA = d_ws;                               // emb7/5/3/1
    void* bufB = (char*)d_ws + (size_t)268435456;    // emb6/4/2

    const void* ein = d_in[8];  // contents8 (fp32) for the fused leaf level
    for (int j = 7; j >= 0; --j) {
        const int n      = in_sizes[j] / 32;
        const int ntiles = n / 16;
        void* eout = (j == 0) ? d_out : ((j & 1) ? bufA : bufB);
        int blocks = ntiles < 4096 ? ntiles : 4096;
        const float* cont  = (const float*)d_in[j];
        const int*   child = (const int*)d_in[9 + j];
        if (j == 7)
            grnn_mfma<true,  false><<<blocks, 256, 0, stream>>>(cont, child, ein, Wu, bu, Wh, bh, eout, ntiles);
        else if (j == 0)
            grnn_mfma<false, true ><<<blocks, 256, 0, stream>>>(cont, child, ein, Wu, bu, Wh, bh, eout, ntiles);
        else
            grnn_mfma<false, false><<<blocks, 256, 0, stream>>>(cont, child, ein, Wu, bu, Wh, bh, eout, ntiles);
        ein = eout;
    }
}